// Round 3
// baseline (660.935 us; speedup 1.0000x reference)
//
#include <hip/hip_runtime.h>
#include <hip/hip_fp16.h>
#include <cstdint>
#include <cstddef>

// GAT on MI355X. Round 18: attn_heads rebuilt as per-(t,i) MFMA block:
// gather 64 nbr rows -> LDS, P[8,64] @ Xg[64,256] via mfma_f32_16x16x32_f16
// (A-frag = P from LDS, B-frag = 8x ds_read_u16, D -> LDS -> coalesced store).
// attn_out reverted to R16 rolling-unroll fdot2 gather. Rest unchanged.
// T=32,N=512,F=256,H=8,L=3.

typedef _Float16 f16x2 __attribute__((ext_vector_type(2)));
typedef _Float16 f16x8 __attribute__((ext_vector_type(8)));
typedef float f32x4 __attribute__((ext_vector_type(4)));
typedef unsigned int uint32;

__device__ __forceinline__ void async_copy16(const void* g, void* l) {
    __builtin_amdgcn_global_load_lds(
        (const __attribute__((address_space(1))) void*)g,
        (__attribute__((address_space(3))) void*)l, 16, 0, 0);
}
__device__ __forceinline__ float fast_elu(float v) {
    return v > 0.f ? v : (__expf(v) - 1.f);
}
__device__ __forceinline__ unsigned short f2h(float f) {
    return __builtin_bit_cast(unsigned short, (_Float16)f);
}
__device__ __forceinline__ float h2f(unsigned short u) {
    return (float)__builtin_bit_cast(_Float16, u);
}

// ---------------- CSR build (ballot compaction, one wave per row) ------------
// Zero-fills slots [cnt, 64) so padded gathers hit row 0 (p=0 kills them).
__global__ __launch_bounds__(256)
void build_csr_kernel(const int* __restrict__ adj, int* __restrict__ cnt,
                      int* __restrict__ idxout)
{
    int row  = blockIdx.x * 4 + (threadIdx.x >> 6);
    int lane = threadIdx.x & 63;
    if (row >= 512) return;
    int base = 0;
    for (int j0 = 0; j0 < 512; j0 += 64) {
        int j = j0 + lane;
        bool pred = adj[row * 512 + j] > 0;
        unsigned long long m = __ballot(pred);
        if (pred) {
            int pos = __popcll(m & ((1ull << lane) - 1ull));
            idxout[row * 512 + base + pos] = j;
        }
        base += __popcll(m);
    }
    int s = base + lane;
    if (s < 64) idxout[row * 512 + s] = 0;   // pad: safe gather, p=0 kills it
    if (lane == 0) cnt[row] = base;
}

// ---------------- weight transpose -> f16 ------------------------------------
__global__ __launch_bounds__(256)
void transpose_f16_kernel(const float* __restrict__ in,
                          unsigned short* __restrict__ ob, int K, int N)
{
    int b = blockIdx.z;
    int k0 = blockIdx.y * 32, n0 = blockIdx.x * 32;
    __shared__ float tile[32][33];
    int tx = threadIdx.x & 31, ty = threadIdx.x >> 5;
    const float* inb = in + (size_t)b * K * N;
    #pragma unroll
    for (int r = 0; r < 32; r += 8)
        tile[ty + r][tx] = inb[(size_t)(k0 + ty + r) * N + n0 + tx];
    __syncthreads();
    unsigned short* obb = ob + (size_t)b * K * N;
    #pragma unroll
    for (int r = 0; r < 32; r += 8)
        obb[(size_t)(n0 + ty + r) * K + k0 + tx] = f2h(tile[tx][ty + r]);
}

// ---------------- w1/w2 = W_h @ a1, W_h @ a2 (per head) ----------------------
__global__ __launch_bounds__(256)
void w12_kernel(const float* __restrict__ W, const float* __restrict__ a,
                float* __restrict__ w1, float* __restrict__ w2)
{
    int b = blockIdx.x, k = threadIdx.x;
    const float* Wb = W + (size_t)b * 256 * 256 + (size_t)k * 256;
    const float* ab = a + (size_t)b * 512;
    float s1 = 0.f, s2 = 0.f;
    for (int n = 0; n < 256; ++n) {
        float w = Wb[n];
        s1 = fmaf(w, ab[n], s1);
        s2 = fmaf(w, ab[256 + n], s2);
    }
    w1[b * 256 + k] = s1;
    w2[b * 256 + k] = s2;
}

// ---------------- fused input projection + layer-0 f/g -----------------------
__global__ __launch_bounds__(256)
void proj_fg_kernel(const float* __restrict__ pose, const float* __restrict__ Wp,
                    const float* __restrict__ bp,
                    const float* __restrict__ w1, const float* __restrict__ w2,
                    unsigned short* __restrict__ xH,
                    float* __restrict__ fbuf, float* __restrict__ gbuf)
{
    int w = threadIdx.x >> 6, lane = threadIdx.x & 63;
    int row = blockIdx.x * 4 + w;
    float p0 = pose[row * 3 + 0], p1 = pose[row * 3 + 1], p2 = pose[row * 3 + 2];
    int c4 = lane * 4;
    float4 w0v = *(const float4*)&Wp[0 * 256 + c4];
    float4 w1v_ = *(const float4*)&Wp[1 * 256 + c4];
    float4 w2v_ = *(const float4*)&Wp[2 * 256 + c4];
    float4 bv = *(const float4*)&bp[c4];
    float4 xv;
    xv.x = fmaf(p0, w0v.x, fmaf(p1, w1v_.x, fmaf(p2, w2v_.x, bv.x)));
    xv.y = fmaf(p0, w0v.y, fmaf(p1, w1v_.y, fmaf(p2, w2v_.y, bv.y)));
    xv.z = fmaf(p0, w0v.z, fmaf(p1, w1v_.z, fmaf(p2, w2v_.z, bv.z)));
    xv.w = fmaf(p0, w0v.w, fmaf(p1, w1v_.w, fmaf(p2, w2v_.w, bv.w)));
    ushort4 b4 = {f2h(xv.x), f2h(xv.y), f2h(xv.z), f2h(xv.w)};
    *(ushort4*)&xH[(size_t)row * 256 + c4] = b4;

    float sf[8], sg[8];
    #pragma unroll
    for (int h = 0; h < 8; ++h) {
        float4 a1 = *(const float4*)&w1[h * 256 + c4];
        float4 a2 = *(const float4*)&w2[h * 256 + c4];
        sf[h] = xv.x * a1.x + xv.y * a1.y + xv.z * a1.z + xv.w * a1.w;
        sg[h] = xv.x * a2.x + xv.y * a2.y + xv.z * a2.z + xv.w * a2.w;
    }
    #pragma unroll
    for (int off = 32; off > 0; off >>= 1)
        #pragma unroll
        for (int h = 0; h < 8; ++h) {
            sf[h] += __shfl_xor(sf[h], off);
            sg[h] += __shfl_xor(sg[h], off);
        }
    if (lane == 0) {
        float4 a = {sf[0], sf[1], sf[2], sf[3]}, b = {sf[4], sf[5], sf[6], sf[7]};
        float4 c = {sg[0], sg[1], sg[2], sg[3]}, d = {sg[4], sg[5], sg[6], sg[7]};
        *(float4*)&fbuf[(size_t)row * 8]     = a;
        *(float4*)&fbuf[(size_t)row * 8 + 4] = b;
        *(float4*)&gbuf[(size_t)row * 8]     = c;
        *(float4*)&gbuf[(size_t)row * 8 + 4] = d;
    }
}

// ---------------- single-product f16 MFMA GEMM, 64x128 tile, BK=64 -----------
__global__ __launch_bounds__(256)
void gemm_mfma_kernel(const unsigned short* __restrict__ A,
                      const unsigned short* __restrict__ B,
                      unsigned short* __restrict__ partB,
                      unsigned short* __restrict__ outB,
                      int M, int N, int Kld, int Klen,
                      long strideAz, long strideBz, long strideCz,
                      int outStride, int colOffZ)
{
    int z = blockIdx.z;
    const unsigned short* az = A + (size_t)z * strideAz;
    const unsigned short* bz = B + (size_t)z * strideBz;
    int m0 = blockIdx.y * 64, n0 = blockIdx.x * 128;

    __shared__ __align__(16) unsigned short lsA[2 * 64 * 32];    // 8KB (2 panels)
    __shared__ __align__(16) unsigned short lsB[2 * 128 * 32];   // 16KB

    int tid = threadIdx.x, w = tid >> 6, lane = tid & 63;
    int qr = w >> 1, qc = w & 1;   // wave: rows qr*32..+32, cols qc*64..+64
    int l15 = lane & 15, kgp = lane >> 4;

    f32x4 acc[2][4];
    #pragma unroll
    for (int i = 0; i < 2; i++)
        #pragma unroll
        for (int j = 0; j < 4; j++)
            acc[i][j] = (f32x4){0.f, 0.f, 0.f, 0.f};

    for (int k0 = 0; k0 < Klen; k0 += 64) {
        __syncthreads();
        // 24 chunks of 1KB: A panels (0-7), B panels (8-23); wave w: 6 chunks
        #pragma unroll
        for (int cc = 0; cc < 6; ++cc) {
            int chunk = w * 6 + cc;
            if (chunk < 8) {
                int pp = chunk >> 2, lc = chunk & 3;
                int g = lc * 64 + lane;
                int row = g >> 2;
                int kg = (g & 3) ^ ((row + (row >> 2)) & 3);
                async_copy16(az + (size_t)(m0 + row) * Kld + k0 + pp * 32 + kg * 8,
                             &lsA[pp * 2048 + (size_t)g * 8]);
            } else {
                int bc = chunk - 8;
                int pp = bc >> 3, lc = bc & 7;
                int g = lc * 64 + lane;
                int row = g >> 2;
                int kg = (g & 3) ^ ((row + (row >> 2)) & 3);
                async_copy16(bz + (size_t)(n0 + row) * Kld + k0 + pp * 32 + kg * 8,
                             &lsB[pp * 4096 + (size_t)g * 8]);
            }
        }
        __syncthreads();

        #pragma unroll
        for (int pp = 0; pp < 2; ++pp) {
            f16x8 fa[2], fb[4];
            #pragma unroll
            for (int tr = 0; tr < 2; ++tr) {
                int row = qr * 32 + tr * 16 + l15;
                int cell = row * 4 + (kgp ^ ((row + (row >> 2)) & 3));
                fa[tr] = *(const f16x8*)&lsA[pp * 2048 + cell * 8];
            }
            #pragma unroll
            for (int tc = 0; tc < 4; ++tc) {
                int nn = qc * 64 + tc * 16 + l15;
                int cell = nn * 4 + (kgp ^ ((nn + (nn >> 2)) & 3));
                fb[tc] = *(const f16x8*)&lsB[pp * 4096 + cell * 8];
            }
            #pragma unroll
            for (int tr = 0; tr < 2; ++tr)
                #pragma unroll
                for (int tc = 0; tc < 4; ++tc)
                    acc[tr][tc] = __builtin_amdgcn_mfma_f32_16x16x32_f16(
                        fa[tr], fb[tc], acc[tr][tc], 0, 0, 0);
        }
    }
    // epilogue: C/D layout col=lane&15, row=(lane>>4)*4+reg  [m89-verified]
    if (outB) {
        #pragma unroll
        for (int tr = 0; tr < 2; ++tr) {
            int rbase = m0 + qr * 32 + tr * 16 + (lane >> 4) * 4;
            #pragma unroll
            for (int tc = 0; tc < 4; ++tc) {
                int col = z * colOffZ + n0 + qc * 64 + tc * 16 + l15;
                #pragma unroll
                for (int r = 0; r < 4; ++r) {
                    float o = fast_elu(acc[tr][tc][r]);
                    outB[(size_t)(rbase + r) * outStride + col] = f2h(o);
                }
            }
        }
    } else {
        unsigned short* Cz = partB + (size_t)z * strideCz;
        #pragma unroll
        for (int tr = 0; tr < 2; ++tr) {
            int rbase = m0 + qr * 32 + tr * 16 + (lane >> 4) * 4;
            #pragma unroll
            for (int tc = 0; tc < 4; ++tc) {
                int col = n0 + qc * 64 + tc * 16 + l15;
                #pragma unroll
                for (int r = 0; r < 4; ++r)
                    Cz[(size_t)(rbase + r) * N + col] = f2h(acc[tr][tc][r]);
            }
        }
    }
}

// ---------------- split-K reduce (f16 partials) -> f16 WhO + out-gat f/g -----
__global__ __launch_bounds__(256)
void reduce_fg_kernel(const unsigned short* __restrict__ part, long partStride,
                      const float* __restrict__ a,
                      unsigned short* __restrict__ whoH,
                      float* __restrict__ fAll, float* __restrict__ gAll, int R)
{
    int row = blockIdx.x * 4 + (threadIdx.x >> 6);
    int lane = threadIdx.x & 63;
    const unsigned short* p0 = part + (size_t)row * 256 + lane * 4;
    ushort4 u0 = *(const ushort4*)p0;
    ushort4 u1 = *(const ushort4*)(p0 + partStride);
    float4 v = {h2f(u0.x) + h2f(u1.x), h2f(u0.y) + h2f(u1.y),
                h2f(u0.z) + h2f(u1.z), h2f(u0.w) + h2f(u1.w)};
    ushort4 b4 = {f2h(v.x), f2h(v.y), f2h(v.z), f2h(v.w)};
    *(ushort4*)&whoH[(size_t)row * 256 + lane * 4] = b4;
    float4 a1 = *(const float4*)&a[lane * 4];
    float4 a2 = *(const float4*)&a[256 + lane * 4];
    float sf = v.x * a1.x + v.y * a1.y + v.z * a1.z + v.w * a1.w;
    float sg = v.x * a2.x + v.y * a2.y + v.z * a2.z + v.w * a2.w;
    #pragma unroll
    for (int off = 32; off > 0; off >>= 1) {
        sf += __shfl_down(sf, off);
        sg += __shfl_down(sg, off);
    }
    if (lane == 0) { fAll[row] = sf; gAll[row] = sg; }
}

// ---------------- head attention via MFMA: one block per (t,i) ---------------
// Y[8h,256c] = P[8,64] @ Xg[64,256].  Wave w: gathers Xg rows 16w..16w+15,
// computes softmax for heads 2w,2w+1, owns output cols w*64..+64.
__global__ __launch_bounds__(256)
void attn_heads_kernel(const unsigned short* __restrict__ xH,
                       const float* __restrict__ fbuf, const float* __restrict__ gbuf,
                       const int* __restrict__ nbr_cnt, const int* __restrict__ nbr_idx,
                       unsigned short* __restrict__ yH, int R)
{
    __shared__ __align__(16) unsigned short Xg[64][256];   // 32KB gathered rows
    __shared__ __align__(16) unsigned short pl[64][16];    // 2KB P (rows 8-15 = 0)
    __shared__ __align__(16) unsigned short yT[8][256];    // 4KB output bounce

    int t = blockIdx.y, i = blockIdx.x;
    int tid = threadIdx.x, w = tid >> 6, L = tid & 63;
    int jc = nbr_cnt[i];
    jc = jc < 64 ? jc : 64;
    const unsigned short* xt = xH + (size_t)t * 512 * 256;
    const int* nrow = nbr_idx + i * 512;

    // slot id (pad-safe) + gather issue: 8 instrs, 2 rows each (dest linear)
    int id0 = nrow[L];
    #pragma unroll
    for (int m = 0; m < 8; ++m) {
        int rw = 16 * w + 2 * m + (L >> 5);
        int idg = __shfl(id0, rw);
        async_copy16(xt + (size_t)idg * 256 + (L & 31) * 8,
                     &Xg[0][0] + (size_t)(16 * w + 2 * m) * 256 + (size_t)L * 8);
    }

    // softmax: wave w owns heads 2w, 2w+1 (no-max: logits bounded)
    bool ok = L < jc;
    float2 fv = *(const float2*)&fbuf[(size_t)(t * 512 + i) * 8 + 2 * w];
    float2 gv = *(const float2*)&gbuf[(size_t)(t * 512 + id0) * 8 + 2 * w];
    float e0 = fv.x + gv.x, e1 = fv.y + gv.y;
    e0 = e0 >= 0.f ? e0 : 0.2f * e0;
    e1 = e1 >= 0.f ? e1 : 0.2f * e1;
    float p0 = ok ? __expf(e0) : 0.f;
    float p1 = ok ? __expf(e1) : 0.f;
    float s0 = p0, s1 = p1;
    #pragma unroll
    for (int off = 32; off > 0; off >>= 1) {
        s0 += __shfl_xor(s0, off);
        s1 += __shfl_xor(s1, off);
    }
    p0 *= (1.f / s0);
    p1 *= (1.f / s1);
    uint32 pk = (uint32)f2h(p0) | ((uint32)f2h(p1) << 16);
    *(uint32*)&pl[L][2 * w] = pk;
    if (w == 0) { uint4 z4 = {0, 0, 0, 0}; *(uint4*)&pl[L][8] = z4; }

    __syncthreads();   // drains global_load_lds (vmcnt0) + pl writes

    // A-frag: P[h=l15][k=g4*8+jj] (rows 8-15 zero); B-frag from Xg columns
    int l15 = L & 15, g4 = L >> 4;
    f16x8 af[2];
    #pragma unroll
    for (int kt = 0; kt < 2; ++kt)
        #pragma unroll
        for (int jj = 0; jj < 8; ++jj)
            af[kt][jj] = __builtin_bit_cast(_Float16, pl[kt * 32 + g4 * 8 + jj][l15]);

    f32x4 acc[4];
    #pragma unroll
    for (int nt = 0; nt < 4; ++nt) acc[nt] = (f32x4){0.f, 0.f, 0.f, 0.f};
    #pragma unroll
    for (int nt = 0; nt < 4; ++nt) {
        int n0 = w * 64 + nt * 16;
        #pragma unroll
        for (int kt = 0; kt < 2; ++kt) {
            f16x8 bf;
            #pragma unroll
            for (int jj = 0; jj < 8; ++jj)
                bf[jj] = __builtin_bit_cast(_Float16, Xg[kt * 32 + g4 * 8 + jj][n0 + l15]);
            acc[nt] = __builtin_amdgcn_mfma_f32_16x16x32_f16(af[kt], bf, acc[nt], 0, 0, 0);
        }
    }
    // D layout: col = l15, row = g4*4 + r; rows 0-7 are heads, 8-15 pad
    if (g4 < 2) {
        #pragma unroll
        for (int nt = 0; nt < 4; ++nt) {
            int col = w * 64 + nt * 16 + l15;
            #pragma unroll
            for (int r = 0; r < 4; ++r)
                yT[g4 * 4 + r][col] = f2h(acc[nt][r]);
        }
    }
    __syncthreads();

    // coalesced store: 8 heads x 256 cols, 16B per thread
    int h = tid >> 5, c8 = (tid & 31) * 8;
    size_t ob = (size_t)h * R * 256 + (size_t)(t * 512 + i) * 256 + c8;
    *(uint4*)&yH[ob] = *(const uint4*)&yT[h][c8];
}

// ---------------- out attention + fused next-layer f/g (R16 structure) -------
__global__ __launch_bounds__(256)
void attn_out_kernel(const unsigned short* __restrict__ whoH,
                     const float* __restrict__ fAll, const float* __restrict__ gAll,
                     const int* __restrict__ nbr_cnt, const int* __restrict__ nbr_idx,
                     unsigned short* __restrict__ xH,
                     const float* __restrict__ w1n, const float* __restrict__ w2n,
                     float* __restrict__ fbuf, float* __restrict__ gbuf)
{
    __shared__ uint32 pp2[4][32];
    int t = blockIdx.y;
    int w = threadIdx.x >> 6;
    int i = blockIdx.x * 4 + w;
    int lane = threadIdx.x & 63;
    const unsigned short* whF = whoH + (size_t)t * 512 * 256;
    int jc = nbr_cnt[i];
    jc = jc < 64 ? jc : 64;

    float fi = fAll[t * 512 + i];
    const float* g = gAll + t * 512;
    bool ok = lane < jc;
    int id = 0;
    float p = 0.f;
    if (ok) {
        id = nbr_idx[i * 512 + lane];
        float ee = fi + g[id];
        float e = ee >= 0.f ? ee : 0.2f * ee;
        p = __expf(e);                       // no-max softmax (bounded logits)
    }
    float s = p;
    #pragma unroll
    for (int off = 32; off > 0; off >>= 1) s += __shfl_xor(s, off);
    p *= (1.f / s);
    float pn = __shfl_xor(p, 1);
    if (!(lane & 1))
        pp2[w][lane >> 1] = (uint32)f2h(p) | ((uint32)f2h(pn) << 16);

    const int* nl = nbr_idx + (size_t)__builtin_amdgcn_readfirstlane(i) * 512;
    int np = (jc + 1) >> 1;
    float4 acc = {0.f, 0.f, 0.f, 0.f};
    int f4 = lane * 4;
    #pragma unroll 4
    for (int q = 0; q < np; ++q) {
        int ia = nl[2 * q], ib = nl[2 * q + 1];
        f16x2 ph = __builtin_bit_cast(f16x2, pp2[w][q]);
        uint2 xa = *(const uint2*)&whF[(size_t)ia * 256 + f4];
        uint2 xb = *(const uint2*)&whF[(size_t)ib * 256 + f4];
        uint32 pr0 = __builtin_amdgcn_perm(xb.x, xa.x, 0x05040100u);
        uint32 pr1 = __builtin_amdgcn_perm(xb.x, xa.x, 0x07060302u);
        uint32 pr2 = __builtin_amdgcn_perm(xb.y, xa.y, 0x05040100u);
        uint32 pr3 = __builtin_amdgcn_perm(xb.y, xa.y, 0x07060302u);
        acc.x = __builtin_amdgcn_fdot2(__builtin_bit_cast(f16x2, pr0), ph, acc.x, false);
        acc.y = __builtin_amdgcn_fdot2(__builtin_bit_cast(f16x2, pr1), ph, acc.y, false);
        acc.z = __builtin_amdgcn_fdot2(__builtin_bit_cast(f16x2, pr2), ph, acc.z, false);
        acc.w = __builtin_amdgcn_fdot2(__builtin_bit_cast(f16x2, pr3), ph, acc.w, false);
    }
    float o[4] = {acc.x, acc.y, acc.z, acc.w};
    #pragma unroll
    for (int k = 0; k < 4; ++k)
        o[k] = fast_elu(fast_elu(o[k]));   // double elu
    float4 ov = {o[0], o[1], o[2], o[3]};
    int row = t * 512 + i;
    ushort4 b4 = {f2h(ov.x), f2h(ov.y), f2h(ov.z), f2h(ov.w)};
    *(ushort4*)&xH[(size_t)row * 256 + f4] = b4;

    if (w1n) {   // fused fg_heads for next layer
        float sf[8], sg[8];
        #pragma unroll
        for (int h = 0; h < 8; ++h) {
            float4 w1v = *(const float4*)&w1n[h * 256 + f4];
            float4 w2v = *(const float4*)&w2n[h * 256 + f4];
            sf[h] = ov.x * w1v.x + ov.y * w1v.y + ov.z * w1v.z + ov.w * w1v.w;
            sg[h] = ov.x * w2v.x + ov.y * w2v.y + ov.z * w2v.z + ov.w * w2v.w;
        }
        #pragma unroll
        for (int off = 32; off > 0; off >>= 1)
            #pragma unroll
            for (int h = 0; h < 8; ++h) {
                sf[h] += __shfl_xor(sf[h], off);
                sg[h] += __shfl_xor(sg[h], off);
            }
        if (lane == 0) {
            float4 a = {sf[0], sf[1], sf[2], sf[3]}, b = {sf[4], sf[5], sf[6], sf[7]};
            float4 cc = {sg[0], sg[1], sg[2], sg[3]}, d = {sg[4], sg[5], sg[6], sg[7]};
            *(float4*)&fbuf[(size_t)row * 8]     = a;
            *(float4*)&fbuf[(size_t)row * 8 + 4] = b;
            *(float4*)&gbuf[(size_t)row * 8]     = cc;
            *(float4*)&gbuf[(size_t)row * 8 + 4] = d;
        }
    }
}

// ---------------- fused pooling + final GEMM ---------------------------------
__global__ __launch_bounds__(256)
void final_kernel(const unsigned short* __restrict__ xH, const float* __restrict__ Wo,
                  const float* __restrict__ bo, float* __restrict__ out)
{
    int t = blockIdx.x, c = threadIdx.x;
    __shared__ float pooled[256];
    float s = 0.f;
    const unsigned short* xt = xH + (size_t)t * 512 * 256;
    for (int n = 0; n < 512; ++n) s += h2f(xt[(size_t)n * 256 + c]);
    pooled[c] = s * (1.f / 512.f);
    __syncthreads();
    float o = bo[c];
    for (int k = 0; k < 256; k++) o = fmaf(pooled[k], Wo[k * 256 + c], o);
    out[t * 256 + c] = o;
}

extern "C" void kernel_launch(void* const* d_in, const int* in_sizes, int n_in,
                              void* d_out, int out_size, void* d_ws, size_t ws_size,
                              hipStream_t stream)
{
    const float* pose   = (const float*)d_in[0];   // [32,512,3]
    const int*   adj    = (const int*)  d_in[1];   // [512,512]
    const float* Wp     = (const float*)d_in[2];   // [3,256]
    const float* bp     = (const float*)d_in[3];   // [256]
    const float* Wh_w   = (const float*)d_in[4];   // [3,8,256,256]
    const float* a_h    = (const float*)d_in[5];   // [3,8,512]
    const float* W_outw = (const float*)d_in[6];   // [3,2048,256]
    const float* a_o    = (const float*)d_in[7];   // [3,512]
    const float* Wo     = (const float*)d_in[8];   // [256,256]
    const float* bo     = (const float*)d_in[9];   // [256]
    float* out = (float*)d_out;                    // [32,256]

    const int T = 32, N = 512, F = 256, H = 8, L = 3, Din = 3;

    auto align256 = [](size_t b) { return (b + 255) & ~(size_t)255; };
    auto need = [&](int TC) -> size_t {
        size_t R = (size_t)TC * N;
        size_t b = 0;
        b += align256(R * F * 2);                    // x f16
        b += align256((size_t)H * R * F * 2);        // y f16
        b += align256(R * (size_t)H * F * 2);        // xcat f16
        b += align256(2 * R * F * 2);                // split-K partials f16
        b += align256(R * F * 2);                    // WhO f16
        b += 2 * align256(R * 8 * 4);                // fbuf,gbuf
        b += 2 * align256(R * 4);                    // fAll,gAll
        b += 2 * align256((size_t)L * H * F * F * 2);// weights f16 (heads+out)
        b += 2 * align256((size_t)L * H * F * 4);    // w1,w2
        b += align256(512 * 4) + align256(512 * 512 * 4);
        return b + 4096;
    };
    int TC = 32;
    while (TC > 1 && need(TC) > ws_size) TC >>= 1;
    size_t R = (size_t)TC * N;

    char* wp = (char*)d_ws;
    auto alloc = [&](size_t bytes) -> char* {
        char* r = wp; wp += (bytes + 255) & ~(size_t)255; return r;
    };
    unsigned short* xB     = (unsigned short*)alloc(R * F * 2);
    unsigned short* yB     = (unsigned short*)alloc((size_t)H * R * F * 2);
    unsigned short* xcatB  = (unsigned short*)alloc(R * (size_t)H * F * 2);
    unsigned short* partBf = (unsigned short*)alloc(2 * R * F * 2);
    unsigned short* whoB   = (unsigned short*)alloc(R * F * 2);
    float*          fbuf   = (float*)alloc(R * 8 * 4);
    float*          gbuf   = (float*)alloc(R * 8 * 4);
    float*          fAll   = (float*)alloc(R * 4);
    float*          gAll   = (float*)alloc(R * 4);
    unsigned short* wtb    = (unsigned short*)alloc((size_t)L * H * F * F * 2);
    unsigned short* wotb   = (unsigned short*)alloc((size_t)L * H * F * F * 2);
    float*          w1     = (float*)alloc((size_t)L * H * F * 4);
    float*          w2     = (float*)alloc((size_t)L * H * F * 4);
    int*            ncnt   = (int*)alloc(512 * 4);
    int*            nidx   = (int*)alloc(512 * 512 * 4);

    build_csr_kernel<<<128, 256, 0, stream>>>(adj, ncnt, nidx);
    transpose_f16_kernel<<<dim3(F / 32, F / 32, L * H), 256, 0, stream>>>(
        Wh_w, wtb, F, F);
    transpose_f16_kernel<<<dim3(F / 32, (H * F) / 32, L), 256, 0, stream>>>(
        W_outw, wotb, H * F, F);
    w12_kernel<<<L * H, 256, 0, stream>>>(Wh_w, a_h, w1, w2);

    for (int t0 = 0; t0 < T; t0 += TC) {
        // fused input projection + layer-0 f/g
        proj_fg_kernel<<<(unsigned)(R / 4), 256, 0, stream>>>(
            pose + (size_t)t0 * N * Din, Wp, bp, w1, w2, xB, fbuf, gbuf);

        for (int l = 0; l < L; l++) {
            // y_h = attn_h @ x  (MFMA per (t,i) block)
            attn_heads_kernel<<<dim3(512, TC), 256, 0, stream>>>(
                xB, fbuf, gbuf, ncnt, nidx, yB, (int)R);
            // xcat[:, h*256:+256] = elu(y_h @ W_h)  (z=8, f16 out)
            gemm_mfma_kernel<<<dim3(F / 128, (unsigned)(R / 64), H), 256, 0, stream>>>(
                yB, wtb + (size_t)l * H * F * F,
                nullptr, xcatB,
                (int)R, F, F, F,
                (long)R * F, (long)F * F, 0, H * F, F);
            // out-proj split-K x2: part[z] = xcat[:, z*1024:+1024] @ W_out chunk
            gemm_mfma_kernel<<<dim3(F / 128, (unsigned)(R / 64), 2), 256, 0, stream>>>(
                xcatB, wotb + (size_t)l * H * F * F,
                partBf, nullptr,
                (int)R, F, H * F, H * F / 2,
                (long)(H * F / 2), (long)(H * F / 2), (long)R * F, 0, 0);
            // WhO(f16) = part0+part1 + out-gat f/g
            reduce_fg_kernel<<<(unsigned)(R / 4), 256, 0, stream>>>(
                partBf, (long)R * F, a_o + (size_t)l * 2 * F, whoB, fAll, gAll, (int)R);
            // x = elu(elu(attn_o @ WhO)); fused f/g for next layer's heads
            const float* w1n = (l + 1 < L) ? w1 + (size_t)(l + 1) * H * F : nullptr;
            const float* w2n = (l + 1 < L) ? w2 + (size_t)(l + 1) * H * F : nullptr;
            attn_out_kernel<<<dim3(128, TC), 256, 0, stream>>>(
                whoB, fAll, gAll, ncnt, nidx, xB, w1n, w2n, fbuf, gbuf);
        }
        final_kernel<<<TC, 256, 0, stream>>>(xB, Wo, bo, out + (size_t)t0 * F);
    }
}

// Round 4
// 552.338 us; speedup vs baseline: 1.1966x; 1.1966x over previous
//
#include <hip/hip_runtime.h>
#include <hip/hip_fp16.h>
#include <cstdint>
#include <cstddef>

// GAT on MI355X. Round 19: attn_heads reverted to R16 (proven 45.6us rolling
// fdot2 gather; two MFMA-attn experiments both regressed). GEMM widened to
// 128x128 tile (4 waves x 64x64, acc[4][4], 32 MFMA/k-step) for better
// MFMA:overhead ratio. T=32,N=512,F=256,H=8,L=3.

typedef _Float16 f16x2 __attribute__((ext_vector_type(2)));
typedef _Float16 f16x8 __attribute__((ext_vector_type(8)));
typedef float f32x4 __attribute__((ext_vector_type(4)));
typedef unsigned int uint32;

__device__ __forceinline__ void async_copy16(const void* g, void* l) {
    __builtin_amdgcn_global_load_lds(
        (const __attribute__((address_space(1))) void*)g,
        (__attribute__((address_space(3))) void*)l, 16, 0, 0);
}
__device__ __forceinline__ float fast_elu(float v) {
    return v > 0.f ? v : (__expf(v) - 1.f);
}
__device__ __forceinline__ unsigned short f2h(float f) {
    return __builtin_bit_cast(unsigned short, (_Float16)f);
}
__device__ __forceinline__ float h2f(unsigned short u) {
    return (float)__builtin_bit_cast(_Float16, u);
}

// ---------------- CSR build (ballot compaction, one wave per row) ------------
// Zero-fills slots [cnt, 64) so paired reads in the attention loops are safe.
__global__ __launch_bounds__(256)
void build_csr_kernel(const int* __restrict__ adj, int* __restrict__ cnt,
                      int* __restrict__ idxout)
{
    int row  = blockIdx.x * 4 + (threadIdx.x >> 6);
    int lane = threadIdx.x & 63;
    if (row >= 512) return;
    int base = 0;
    for (int j0 = 0; j0 < 512; j0 += 64) {
        int j = j0 + lane;
        bool pred = adj[row * 512 + j] > 0;
        unsigned long long m = __ballot(pred);
        if (pred) {
            int pos = __popcll(m & ((1ull << lane) - 1ull));
            idxout[row * 512 + base + pos] = j;
        }
        base += __popcll(m);
    }
    int s = base + lane;
    if (s < 64) idxout[row * 512 + s] = 0;   // pad: safe gather, p=0 kills it
    if (lane == 0) cnt[row] = base;
}

// ---------------- weight transpose -> f16 ------------------------------------
__global__ __launch_bounds__(256)
void transpose_f16_kernel(const float* __restrict__ in,
                          unsigned short* __restrict__ ob, int K, int N)
{
    int b = blockIdx.z;
    int k0 = blockIdx.y * 32, n0 = blockIdx.x * 32;
    __shared__ float tile[32][33];
    int tx = threadIdx.x & 31, ty = threadIdx.x >> 5;
    const float* inb = in + (size_t)b * K * N;
    #pragma unroll
    for (int r = 0; r < 32; r += 8)
        tile[ty + r][tx] = inb[(size_t)(k0 + ty + r) * N + n0 + tx];
    __syncthreads();
    unsigned short* obb = ob + (size_t)b * K * N;
    #pragma unroll
    for (int r = 0; r < 32; r += 8)
        obb[(size_t)(n0 + ty + r) * K + k0 + tx] = f2h(tile[tx][ty + r]);
}

// ---------------- w1/w2 = W_h @ a1, W_h @ a2 (per head) ----------------------
__global__ __launch_bounds__(256)
void w12_kernel(const float* __restrict__ W, const float* __restrict__ a,
                float* __restrict__ w1, float* __restrict__ w2)
{
    int b = blockIdx.x, k = threadIdx.x;
    const float* Wb = W + (size_t)b * 256 * 256 + (size_t)k * 256;
    const float* ab = a + (size_t)b * 512;
    float s1 = 0.f, s2 = 0.f;
    for (int n = 0; n < 256; ++n) {
        float w = Wb[n];
        s1 = fmaf(w, ab[n], s1);
        s2 = fmaf(w, ab[256 + n], s2);
    }
    w1[b * 256 + k] = s1;
    w2[b * 256 + k] = s2;
}

// ---------------- fused input projection + layer-0 f/g -----------------------
__global__ __launch_bounds__(256)
void proj_fg_kernel(const float* __restrict__ pose, const float* __restrict__ Wp,
                    const float* __restrict__ bp,
                    const float* __restrict__ w1, const float* __restrict__ w2,
                    unsigned short* __restrict__ xH,
                    float* __restrict__ fbuf, float* __restrict__ gbuf)
{
    int w = threadIdx.x >> 6, lane = threadIdx.x & 63;
    int row = blockIdx.x * 4 + w;
    float p0 = pose[row * 3 + 0], p1 = pose[row * 3 + 1], p2 = pose[row * 3 + 2];
    int c4 = lane * 4;
    float4 w0v = *(const float4*)&Wp[0 * 256 + c4];
    float4 w1v_ = *(const float4*)&Wp[1 * 256 + c4];
    float4 w2v_ = *(const float4*)&Wp[2 * 256 + c4];
    float4 bv = *(const float4*)&bp[c4];
    float4 xv;
    xv.x = fmaf(p0, w0v.x, fmaf(p1, w1v_.x, fmaf(p2, w2v_.x, bv.x)));
    xv.y = fmaf(p0, w0v.y, fmaf(p1, w1v_.y, fmaf(p2, w2v_.y, bv.y)));
    xv.z = fmaf(p0, w0v.z, fmaf(p1, w1v_.z, fmaf(p2, w2v_.z, bv.z)));
    xv.w = fmaf(p0, w0v.w, fmaf(p1, w1v_.w, fmaf(p2, w2v_.w, bv.w)));
    ushort4 b4 = {f2h(xv.x), f2h(xv.y), f2h(xv.z), f2h(xv.w)};
    *(ushort4*)&xH[(size_t)row * 256 + c4] = b4;

    float sf[8], sg[8];
    #pragma unroll
    for (int h = 0; h < 8; ++h) {
        float4 a1 = *(const float4*)&w1[h * 256 + c4];
        float4 a2 = *(const float4*)&w2[h * 256 + c4];
        sf[h] = xv.x * a1.x + xv.y * a1.y + xv.z * a1.z + xv.w * a1.w;
        sg[h] = xv.x * a2.x + xv.y * a2.y + xv.z * a2.z + xv.w * a2.w;
    }
    #pragma unroll
    for (int off = 32; off > 0; off >>= 1)
        #pragma unroll
        for (int h = 0; h < 8; ++h) {
            sf[h] += __shfl_xor(sf[h], off);
            sg[h] += __shfl_xor(sg[h], off);
        }
    if (lane == 0) {
        float4 a = {sf[0], sf[1], sf[2], sf[3]}, b = {sf[4], sf[5], sf[6], sf[7]};
        float4 c = {sg[0], sg[1], sg[2], sg[3]}, d = {sg[4], sg[5], sg[6], sg[7]};
        *(float4*)&fbuf[(size_t)row * 8]     = a;
        *(float4*)&fbuf[(size_t)row * 8 + 4] = b;
        *(float4*)&gbuf[(size_t)row * 8]     = c;
        *(float4*)&gbuf[(size_t)row * 8 + 4] = d;
    }
}

// ---------------- single-product f16 MFMA GEMM, 128x128 tile, BK=64 ----------
// C[z] = A@B^T (fp32 acc). A: [M][Kld] f16 (+z*strideAz), k in [0,Klen).
// B: [N][Kld] f16 (+z*strideBz). Klen % 64 == 0, M % 128 == 0.
// outB!=null: fast_elu + f16 store at row*outStride + z*colOffZ + col.
// else: plain f16 partial to partB + z*strideCz (elements), row stride N.
__global__ __launch_bounds__(256)
void gemm_mfma_kernel(const unsigned short* __restrict__ A,
                      const unsigned short* __restrict__ B,
                      unsigned short* __restrict__ partB,
                      unsigned short* __restrict__ outB,
                      int M, int N, int Kld, int Klen,
                      long strideAz, long strideBz, long strideCz,
                      int outStride, int colOffZ)
{
    int z = blockIdx.z;
    const unsigned short* az = A + (size_t)z * strideAz;
    const unsigned short* bz = B + (size_t)z * strideBz;
    int m0 = blockIdx.y * 128, n0 = blockIdx.x * 128;

    __shared__ __align__(16) unsigned short lsA[2 * 128 * 32];   // 16KB (2 panels)
    __shared__ __align__(16) unsigned short lsB[2 * 128 * 32];   // 16KB

    int tid = threadIdx.x, w = tid >> 6, lane = tid & 63;
    int qr = w >> 1, qc = w & 1;   // wave: rows qr*64..+64, cols qc*64..+64
    int l15 = lane & 15, kgp = lane >> 4;

    f32x4 acc[4][4];
    #pragma unroll
    for (int i = 0; i < 4; i++)
        #pragma unroll
        for (int j = 0; j < 4; j++)
            acc[i][j] = (f32x4){0.f, 0.f, 0.f, 0.f};

    for (int k0 = 0; k0 < Klen; k0 += 64) {
        __syncthreads();
        // 32 chunks of 1KB: A panels (0-15), B panels (16-31); wave w: 8 chunks
        #pragma unroll
        for (int cc = 0; cc < 8; ++cc) {
            int chunk = w * 8 + cc;
            if (chunk < 16) {
                int pp = chunk >> 3, lc = chunk & 7;
                int g = lc * 64 + lane;
                int row = g >> 2;
                int kg = (g & 3) ^ ((row + (row >> 2)) & 3);
                async_copy16(az + (size_t)(m0 + row) * Kld + k0 + pp * 32 + kg * 8,
                             &lsA[pp * 4096 + (size_t)g * 8]);
            } else {
                int bc = chunk - 16;
                int pp = bc >> 3, lc = bc & 7;
                int g = lc * 64 + lane;
                int row = g >> 2;
                int kg = (g & 3) ^ ((row + (row >> 2)) & 3);
                async_copy16(bz + (size_t)(n0 + row) * Kld + k0 + pp * 32 + kg * 8,
                             &lsB[pp * 4096 + (size_t)g * 8]);
            }
        }
        __syncthreads();

        #pragma unroll
        for (int pp = 0; pp < 2; ++pp) {
            f16x8 fa[4], fb[4];
            #pragma unroll
            for (int tr = 0; tr < 4; ++tr) {
                int row = qr * 64 + tr * 16 + l15;
                int cell = row * 4 + (kgp ^ ((row + (row >> 2)) & 3));
                fa[tr] = *(const f16x8*)&lsA[pp * 4096 + cell * 8];
            }
            #pragma unroll
            for (int tc = 0; tc < 4; ++tc) {
                int nn = qc * 64 + tc * 16 + l15;
                int cell = nn * 4 + (kgp ^ ((nn + (nn >> 2)) & 3));
                fb[tc] = *(const f16x8*)&lsB[pp * 4096 + cell * 8];
            }
            #pragma unroll
            for (int tr = 0; tr < 4; ++tr)
                #pragma unroll
                for (int tc = 0; tc < 4; ++tc)
                    acc[tr][tc] = __builtin_amdgcn_mfma_f32_16x16x32_f16(
                        fa[tr], fb[tc], acc[tr][tc], 0, 0, 0);
        }
    }
    // epilogue: C/D layout col=lane&15, row=(lane>>4)*4+reg  [m89-verified]
    if (outB) {
        #pragma unroll
        for (int tr = 0; tr < 4; ++tr) {
            int rbase = m0 + qr * 64 + tr * 16 + (lane >> 4) * 4;
            #pragma unroll
            for (int tc = 0; tc < 4; ++tc) {
                int col = z * colOffZ + n0 + qc * 64 + tc * 16 + l15;
                #pragma unroll
                for (int r = 0; r < 4; ++r) {
                    float o = fast_elu(acc[tr][tc][r]);
                    outB[(size_t)(rbase + r) * outStride + col] = f2h(o);
                }
            }
        }
    } else {
        unsigned short* Cz = partB + (size_t)z * strideCz;
        #pragma unroll
        for (int tr = 0; tr < 4; ++tr) {
            int rbase = m0 + qr * 64 + tr * 16 + (lane >> 4) * 4;
            #pragma unroll
            for (int tc = 0; tc < 4; ++tc) {
                int col = n0 + qc * 64 + tc * 16 + l15;
                #pragma unroll
                for (int r = 0; r < 4; ++r)
                    Cz[(size_t)(rbase + r) * N + col] = f2h(acc[tr][tc][r]);
            }
        }
    }
}

// ---------------- split-K reduce (f16 partials) -> f16 WhO + out-gat f/g -----
__global__ __launch_bounds__(256)
void reduce_fg_kernel(const unsigned short* __restrict__ part, long partStride,
                      const float* __restrict__ a,
                      unsigned short* __restrict__ whoH,
                      float* __restrict__ fAll, float* __restrict__ gAll, int R)
{
    int row = blockIdx.x * 4 + (threadIdx.x >> 6);
    int lane = threadIdx.x & 63;
    const unsigned short* p0 = part + (size_t)row * 256 + lane * 4;
    ushort4 u0 = *(const ushort4*)p0;
    ushort4 u1 = *(const ushort4*)(p0 + partStride);
    float4 v = {h2f(u0.x) + h2f(u1.x), h2f(u0.y) + h2f(u1.y),
                h2f(u0.z) + h2f(u1.z), h2f(u0.w) + h2f(u1.w)};
    ushort4 b4 = {f2h(v.x), f2h(v.y), f2h(v.z), f2h(v.w)};
    *(ushort4*)&whoH[(size_t)row * 256 + lane * 4] = b4;
    float4 a1 = *(const float4*)&a[lane * 4];
    float4 a2 = *(const float4*)&a[256 + lane * 4];
    float sf = v.x * a1.x + v.y * a1.y + v.z * a1.z + v.w * a1.w;
    float sg = v.x * a2.x + v.y * a2.y + v.z * a2.z + v.w * a2.w;
    #pragma unroll
    for (int off = 32; off > 0; off >>= 1) {
        sf += __shfl_down(sf, off);
        sg += __shfl_down(sg, off);
    }
    if (lane == 0) { fAll[row] = sf; gAll[row] = sg; }
}

// ---------------- head attention: y_h = attn_h @ x, all 8 heads per wave -----
// R16 rolling fdot2 gather (proven): paired neighbors, p-pairs in LDS,
// per-iteration uniform nl loads, #pragma unroll 4 pipeline.
__global__ __launch_bounds__(256)
void attn_heads_kernel(const unsigned short* __restrict__ xH,
                       const float* __restrict__ fbuf, const float* __restrict__ gbuf,
                       const int* __restrict__ nbr_cnt, const int* __restrict__ nbr_idx,
                       unsigned short* __restrict__ yH, int R)
{
    __shared__ uint32 ppk[4][32][8];   // [wave][pair][head] f16x2(p_a,p_b)
    int t = blockIdx.y;
    int w = threadIdx.x >> 6;
    int i = blockIdx.x * 4 + w;
    int lane = threadIdx.x & 63;
    int jc = nbr_cnt[i];
    jc = jc < 64 ? jc : 64;
    int row = t * 512 + i;
    const unsigned short* xt = xH + (size_t)t * 512 * 256;

    float4 fA = *(const float4*)&fbuf[(size_t)row * 8];
    float4 fB = *(const float4*)&fbuf[(size_t)row * 8 + 4];

    bool ok = lane < jc;
    float4 gA = {0.f, 0.f, 0.f, 0.f}, gB = {0.f, 0.f, 0.f, 0.f};
    if (ok) {
        int id = nbr_idx[i * 512 + lane];
        const float* gp = &gbuf[(size_t)(t * 512 + id) * 8];
        gA = *(const float4*)gp;
        gB = *(const float4*)(gp + 4);
    }
    float e[8];
    e[0] = fA.x + gA.x; e[1] = fA.y + gA.y; e[2] = fA.z + gA.z; e[3] = fA.w + gA.w;
    e[4] = fB.x + gB.x; e[5] = fB.y + gB.y; e[6] = fB.z + gB.z; e[7] = fB.w + gB.w;
    float p[8];
    #pragma unroll
    for (int h = 0; h < 8; ++h) {
        float eh = e[h] >= 0.f ? e[h] : 0.2f * e[h];
        float pe = ok ? __expf(eh) : 0.f;     // no-max softmax (bounded logits)
        float s = pe;
        #pragma unroll
        for (int off = 32; off > 0; off >>= 1) s += __shfl_xor(s, off);
        p[h] = pe * (1.f / s);
    }
    // pack neighbor-pairs (p_2q low, p_2q+1 high), RNE per element
    uint32 u[8];
    #pragma unroll
    for (int h = 0; h < 8; ++h) {
        float pn = __shfl_xor(p[h], 1);
        u[h] = (uint32)f2h(p[h]) | ((uint32)f2h(pn) << 16);
    }
    if (!(lane & 1)) {
        int q = lane >> 1;
        uint4 lo = {u[0], u[1], u[2], u[3]}, hi = {u[4], u[5], u[6], u[7]};
        *(uint4*)&ppk[w][q][0] = lo;       // wave-local: no barrier needed
        *(uint4*)&ppk[w][q][4] = hi;
    }

    const int* nl = nbr_idx + (size_t)__builtin_amdgcn_readfirstlane(i) * 512;
    int np = (jc + 1) >> 1;
    float4 acc[8];
    #pragma unroll
    for (int h = 0; h < 8; ++h) acc[h] = (float4){0.f, 0.f, 0.f, 0.f};
    int f4 = lane * 4;
    #pragma unroll 4
    for (int q = 0; q < np; ++q) {
        int ia = nl[2 * q], ib = nl[2 * q + 1];      // s_load (uniform)
        uint4 plo = *(const uint4*)&ppk[w][q][0];
        uint4 phi = *(const uint4*)&ppk[w][q][4];
        uint2 xa = *(const uint2*)&xt[(size_t)ia * 256 + f4];
        uint2 xb = *(const uint2*)&xt[(size_t)ib * 256 + f4];
        uint32 pr0 = __builtin_amdgcn_perm(xb.x, xa.x, 0x05040100u);  // (xa.c0,xb.c0)
        uint32 pr1 = __builtin_amdgcn_perm(xb.x, xa.x, 0x07060302u);  // (xa.c1,xb.c1)
        uint32 pr2 = __builtin_amdgcn_perm(xb.y, xa.y, 0x05040100u);
        uint32 pr3 = __builtin_amdgcn_perm(xb.y, xa.y, 0x07060302u);
        f16x2 c0 = __builtin_bit_cast(f16x2, pr0);
        f16x2 c1 = __builtin_bit_cast(f16x2, pr1);
        f16x2 c2 = __builtin_bit_cast(f16x2, pr2);
        f16x2 c3 = __builtin_bit_cast(f16x2, pr3);
        uint32 pw[8] = {plo.x, plo.y, plo.z, plo.w, phi.x, phi.y, phi.z, phi.w};
        #pragma unroll
        for (int h = 0; h < 8; ++h) {
            f16x2 ph = __builtin_bit_cast(f16x2, pw[h]);
            acc[h].x = __builtin_amdgcn_fdot2(c0, ph, acc[h].x, false);
            acc[h].y = __builtin_amdgcn_fdot2(c1, ph, acc[h].y, false);
            acc[h].z = __builtin_amdgcn_fdot2(c2, ph, acc[h].z, false);
            acc[h].w = __builtin_amdgcn_fdot2(c3, ph, acc[h].w, false);
        }
    }

    #pragma unroll
    for (int h = 0; h < 8; ++h) {
        ushort4 b4 = {f2h(acc[h].x), f2h(acc[h].y), f2h(acc[h].z), f2h(acc[h].w)};
        size_t ob = (size_t)h * R * 256 + (size_t)row * 256 + f4;
        *(ushort4*)&yH[ob] = b4;
    }
}

// ---------------- out attention + fused next-layer f/g (R16 structure) -------
__global__ __launch_bounds__(256)
void attn_out_kernel(const unsigned short* __restrict__ whoH,
                     const float* __restrict__ fAll, const float* __restrict__ gAll,
                     const int* __restrict__ nbr_cnt, const int* __restrict__ nbr_idx,
                     unsigned short* __restrict__ xH,
                     const float* __restrict__ w1n, const float* __restrict__ w2n,
                     float* __restrict__ fbuf, float* __restrict__ gbuf)
{
    __shared__ uint32 pp2[4][32];
    int t = blockIdx.y;
    int w = threadIdx.x >> 6;
    int i = blockIdx.x * 4 + w;
    int lane = threadIdx.x & 63;
    const unsigned short* whF = whoH + (size_t)t * 512 * 256;
    int jc = nbr_cnt[i];
    jc = jc < 64 ? jc : 64;

    float fi = fAll[t * 512 + i];
    const float* g = gAll + t * 512;
    bool ok = lane < jc;
    int id = 0;
    float p = 0.f;
    if (ok) {
        id = nbr_idx[i * 512 + lane];
        float ee = fi + g[id];
        float e = ee >= 0.f ? ee : 0.2f * ee;
        p = __expf(e);                       // no-max softmax (bounded logits)
    }
    float s = p;
    #pragma unroll
    for (int off = 32; off > 0; off >>= 1) s += __shfl_xor(s, off);
    p *= (1.f / s);
    float pn = __shfl_xor(p, 1);
    if (!(lane & 1))
        pp2[w][lane >> 1] = (uint32)f2h(p) | ((uint32)f2h(pn) << 16);

    const int* nl = nbr_idx + (size_t)__builtin_amdgcn_readfirstlane(i) * 512;
    int np = (jc + 1) >> 1;
    float4 acc = {0.f, 0.f, 0.f, 0.f};
    int f4 = lane * 4;
    #pragma unroll 4
    for (int q = 0; q < np; ++q) {
        int ia = nl[2 * q], ib = nl[2 * q + 1];
        f16x2 ph = __builtin_bit_cast(f16x2, pp2[w][q]);
        uint2 xa = *(const uint2*)&whF[(size_t)ia * 256 + f4];
        uint2 xb = *(const uint2*)&whF[(size_t)ib * 256 + f4];
        uint32 pr0 = __builtin_amdgcn_perm(xb.x, xa.x, 0x05040100u);
        uint32 pr1 = __builtin_amdgcn_perm(xb.x, xa.x, 0x07060302u);
        uint32 pr2 = __builtin_amdgcn_perm(xb.y, xa.y, 0x05040100u);
        uint32 pr3 = __builtin_amdgcn_perm(xb.y, xa.y, 0x07060302u);
        acc.x = __builtin_amdgcn_fdot2(__builtin_bit_cast(f16x2, pr0), ph, acc.x, false);
        acc.y = __builtin_amdgcn_fdot2(__builtin_bit_cast(f16x2, pr1), ph, acc.y, false);
        acc.z = __builtin_amdgcn_fdot2(__builtin_bit_cast(f16x2, pr2), ph, acc.z, false);
        acc.w = __builtin_amdgcn_fdot2(__builtin_bit_cast(f16x2, pr3), ph, acc.w, false);
    }
    float o[4] = {acc.x, acc.y, acc.z, acc.w};
    #pragma unroll
    for (int k = 0; k < 4; ++k)
        o[k] = fast_elu(fast_elu(o[k]));   // double elu
    float4 ov = {o[0], o[1], o[2], o[3]};
    int row = t * 512 + i;
    ushort4 b4 = {f2h(ov.x), f2h(ov.y), f2h(ov.z), f2h(ov.w)};
    *(ushort4*)&xH[(size_t)row * 256 + f4] = b4;

    if (w1n) {   // fused fg_heads for next layer
        float sf[8], sg[8];
        #pragma unroll
        for (int h = 0; h < 8; ++h) {
            float4 w1v = *(const float4*)&w1n[h * 256 + f4];
            float4 w2v = *(const float4*)&w2n[h * 256 + f4];
            sf[h] = ov.x * w1v.x + ov.y * w1v.y + ov.z * w1v.z + ov.w * w1v.w;
            sg[h] = ov.x * w2v.x + ov.y * w2v.y + ov.z * w2v.z + ov.w * w2v.w;
        }
        #pragma unroll
        for (int off = 32; off > 0; off >>= 1)
            #pragma unroll
            for (int h = 0; h < 8; ++h) {
                sf[h] += __shfl_xor(sf[h], off);
                sg[h] += __shfl_xor(sg[h], off);
            }
        if (lane == 0) {
            float4 a = {sf[0], sf[1], sf[2], sf[3]}, b = {sf[4], sf[5], sf[6], sf[7]};
            float4 cc = {sg[0], sg[1], sg[2], sg[3]}, d = {sg[4], sg[5], sg[6], sg[7]};
            *(float4*)&fbuf[(size_t)row * 8]     = a;
            *(float4*)&fbuf[(size_t)row * 8 + 4] = b;
            *(float4*)&gbuf[(size_t)row * 8]     = cc;
            *(float4*)&gbuf[(size_t)row * 8 + 4] = d;
        }
    }
}

// ---------------- fused pooling + final GEMM ---------------------------------
__global__ __launch_bounds__(256)
void final_kernel(const unsigned short* __restrict__ xH, const float* __restrict__ Wo,
                  const float* __restrict__ bo, float* __restrict__ out)
{
    int t = blockIdx.x, c = threadIdx.x;
    __shared__ float pooled[256];
    float s = 0.f;
    const unsigned short* xt = xH + (size_t)t * 512 * 256;
    for (int n = 0; n < 512; ++n) s += h2f(xt[(size_t)n * 256 + c]);
    pooled[c] = s * (1.f / 512.f);
    __syncthreads();
    float o = bo[c];
    for (int k = 0; k < 256; k++) o = fmaf(pooled[k], Wo[k * 256 + c], o);
    out[t * 256 + c] = o;
}

extern "C" void kernel_launch(void* const* d_in, const int* in_sizes, int n_in,
                              void* d_out, int out_size, void* d_ws, size_t ws_size,
                              hipStream_t stream)
{
    const float* pose   = (const float*)d_in[0];   // [32,512,3]
    const int*   adj    = (const int*)  d_in[1];   // [512,512]
    const float* Wp     = (const float*)d_in[2];   // [3,256]
    const float* bp     = (const float*)d_in[3];   // [256]
    const float* Wh_w   = (const float*)d_in[4];   // [3,8,256,256]
    const float* a_h    = (const float*)d_in[5];   // [3,8,512]
    const float* W_outw = (const float*)d_in[6];   // [3,2048,256]
    const float* a_o    = (const float*)d_in[7];   // [3,512]
    const float* Wo     = (const float*)d_in[8];   // [256,256]
    const float* bo     = (const float*)d_in[9];   // [256]
    float* out = (float*)d_out;                    // [32,256]

    const int T = 32, N = 512, F = 256, H = 8, L = 3, Din = 3;

    auto align256 = [](size_t b) { return (b + 255) & ~(size_t)255; };
    auto need = [&](int TC) -> size_t {
        size_t R = (size_t)TC * N;
        size_t b = 0;
        b += align256(R * F * 2);                    // x f16
        b += align256((size_t)H * R * F * 2);        // y f16
        b += align256(R * (size_t)H * F * 2);        // xcat f16
        b += align256(2 * R * F * 2);                // split-K partials f16
        b += align256(R * F * 2);                    // WhO f16
        b += 2 * align256(R * 8 * 4);                // fbuf,gbuf
        b += 2 * align256(R * 4);                    // fAll,gAll
        b += 2 * align256((size_t)L * H * F * F * 2);// weights f16 (heads+out)
        b += 2 * align256((size_t)L * H * F * 4);    // w1,w2
        b += align256(512 * 4) + align256(512 * 512 * 4);
        return b + 4096;
    };
    int TC = 32;
    while (TC > 1 && need(TC) > ws_size) TC >>= 1;
    size_t R = (size_t)TC * N;

    char* wp = (char*)d_ws;
    auto alloc = [&](size_t bytes) -> char* {
        char* r = wp; wp += (bytes + 255) & ~(size_t)255; return r;
    };
    unsigned short* xB     = (unsigned short*)alloc(R * F * 2);
    unsigned short* yB     = (unsigned short*)alloc((size_t)H * R * F * 2);
    unsigned short* xcatB  = (unsigned short*)alloc(R * (size_t)H * F * 2);
    unsigned short* partBf = (unsigned short*)alloc(2 * R * F * 2);
    unsigned short* whoB   = (unsigned short*)alloc(R * F * 2);
    float*          fbuf   = (float*)alloc(R * 8 * 4);
    float*          gbuf   = (float*)alloc(R * 8 * 4);
    float*          fAll   = (float*)alloc(R * 4);
    float*          gAll   = (float*)alloc(R * 4);
    unsigned short* wtb    = (unsigned short*)alloc((size_t)L * H * F * F * 2);
    unsigned short* wotb   = (unsigned short*)alloc((size_t)L * H * F * F * 2);
    float*          w1     = (float*)alloc((size_t)L * H * F * 4);
    float*          w2     = (float*)alloc((size_t)L * H * F * 4);
    int*            ncnt   = (int*)alloc(512 * 4);
    int*            nidx   = (int*)alloc(512 * 512 * 4);

    build_csr_kernel<<<128, 256, 0, stream>>>(adj, ncnt, nidx);
    transpose_f16_kernel<<<dim3(F / 32, F / 32, L * H), 256, 0, stream>>>(
        Wh_w, wtb, F, F);
    transpose_f16_kernel<<<dim3(F / 32, (H * F) / 32, L), 256, 0, stream>>>(
        W_outw, wotb, H * F, F);
    w12_kernel<<<L * H, 256, 0, stream>>>(Wh_w, a_h, w1, w2);

    for (int t0 = 0; t0 < T; t0 += TC) {
        // fused input projection + layer-0 f/g
        proj_fg_kernel<<<(unsigned)(R / 4), 256, 0, stream>>>(
            pose + (size_t)t0 * N * Din, Wp, bp, w1, w2, xB, fbuf, gbuf);

        for (int l = 0; l < L; l++) {
            // y_h = attn_h @ x  (R16 rolling dot2 gather for all 8 heads)
            attn_heads_kernel<<<dim3(128, TC), 256, 0, stream>>>(
                xB, fbuf, gbuf, ncnt, nidx, yB, (int)R);
            // xcat[:, h*256:+256] = elu(y_h @ W_h)  (z=8, f16 out)
            gemm_mfma_kernel<<<dim3(F / 128, (unsigned)(R / 128), H), 256, 0, stream>>>(
                yB, wtb + (size_t)l * H * F * F,
                nullptr, xcatB,
                (int)R, F, F, F,
                (long)R * F, (long)F * F, 0, H * F, F);
            // out-proj split-K x2: part[z] = xcat[:, z*1024:+1024] @ W_out chunk
            gemm_mfma_kernel<<<dim3(F / 128, (unsigned)(R / 128), 2), 256, 0, stream>>>(
                xcatB, wotb + (size_t)l * H * F * F,
                partBf, nullptr,
                (int)R, F, H * F, H * F / 2,
                (long)(H * F / 2), (long)(H * F / 2), (long)R * F, 0, 0);
            // WhO(f16) = part0+part1 + out-gat f/g
            reduce_fg_kernel<<<(unsigned)(R / 4), 256, 0, stream>>>(
                partBf, (long)R * F, a_o + (size_t)l * 2 * F, whoB, fAll, gAll, (int)R);
            // x = elu(elu(attn_o @ WhO)); fused f/g for next layer's heads
            const float* w1n = (l + 1 < L) ? w1 + (size_t)(l + 1) * H * F : nullptr;
            const float* w2n = (l + 1 < L) ? w2 + (size_t)(l + 1) * H * F : nullptr;
            attn_out_kernel<<<dim3(128, TC), 256, 0, stream>>>(
                whoB, fAll, gAll, ncnt, nidx, xB, w1n, w2n, fbuf, gbuf);
        }
        final_kernel<<<TC, 256, 0, stream>>>(xB, Wo, bo, out + (size_t)t0 * F);
    }
}